// Round 5
// baseline (2807.869 us; speedup 1.0000x reference)
//
#include <hip/hip_runtime.h>
#include <hip/hip_bf16.h>
#include <math.h>

#define RSQ 0.99999500003749969f   // 1/sqrt(1+1e-5)
#define SLOPE 0.01f

typedef __attribute__((ext_vector_type(8))) short short8;
typedef __attribute__((ext_vector_type(4))) float f32x4;

__device__ __forceinline__ float sigmoidf_(float x){ return 1.0f/(1.0f+expf(-x)); }

__device__ __forceinline__ unsigned short f2bf(float f){
    unsigned u = __float_as_uint(f);
    u += 0x7fff + ((u >> 16) & 1);      // RNE
    return (unsigned short)(u >> 16);
}
__device__ __forceinline__ float bf2f(unsigned short s){
    return __uint_as_float(((unsigned)s) << 16);
}

// ---------------- mask: prod_k cos(fW*rng + fB) ----------------
__global__ void mask_partial_kernel(const float* __restrict__ fW, const float* __restrict__ fB,
                                    float* __restrict__ partial)
{
    int p = blockIdx.x*256 + threadIdx.x;   // 0..15902
    if (p >= 15903) return;
    int w = p % 513;
    float r = (float)(w + 1);
    int k0 = blockIdx.y * 32;
    float prod = 1.0f;
    for (int k = k0; k < k0 + 32; ++k) {
        float a = fW[(size_t)k*15903 + p] * r + fB[(size_t)k*15903 + p];
        prod *= cosf(a);
    }
    partial[blockIdx.y*15903 + p] = prod;
}

__global__ void mask_finalize_apply(const float* __restrict__ partial, const float* __restrict__ x,
                                    float* __restrict__ xm)
{
    int p = blockIdx.x*256 + threadIdx.x;
    if (p >= 15903) return;
    float m = 1.0f;
    #pragma unroll
    for (int c = 0; c < 32; ++c) m *= partial[c*15903 + p];
    for (int n = 0; n < 32; ++n)
        xm[(size_t)n*15903 + p] = x[(size_t)n*15903 + p] * m;
}

// ---------------- weight transforms ----------------
// OIHW fp32 -> [tap][co][ci] bf16
__global__ void wtrans9_kernel(const float* __restrict__ w, unsigned short* __restrict__ o,
                               int Cout, int Cin)
{
    int idx = blockIdx.x*256 + threadIdx.x;
    int cc = Cout*Cin;
    if (idx >= 9*cc) return;
    int tap = idx / cc;
    int r = idx - tap*cc;
    int co = r / Cin, ci = r - co*Cin;
    int kh = tap/3, kw = tap - kh*3;
    o[idx] = f2bf(w[((size_t)(co*Cin + ci)*3 + kh)*3 + kw]);
}
__global__ void wtrans1_kernel(const float* __restrict__ w, unsigned short* __restrict__ o, int total)
{
    int idx = blockIdx.x*256 + threadIdx.x;
    if (idx < total) o[idx] = f2bf(w[idx]);
}

// whh (1024,256) fp32 -> MFMA-fragment-contiguous bf16:
// out[g][u0][kc][lane][e], j = 256g + 16u0 + (lane&15), k = 32kc + 8(lane>>4) + e
__global__ void whh_frag_kernel(const float* __restrict__ whh, unsigned short* __restrict__ out)
{
    int tid = blockIdx.x*256 + threadIdx.x;  // 262144 exact
    int e    = tid & 7;
    int lane = (tid >> 3) & 63;
    int kc   = (tid >> 9) & 7;
    int u0   = (tid >> 12) & 15;
    int g    = tid >> 16;
    int j = (g << 8) + (u0 << 4) + (lane & 15);
    int k = (kc << 5) + ((lane >> 4) << 3) + e;
    out[tid] = f2bf(whh[(size_t)j*256 + k]);
}

// ---------------- conv1: Cin=1 direct, fp32 in -> bf16 NHWC out ----------------
__launch_bounds__(256)
__global__ void conv1_kernel(const float* __restrict__ xm, const float* __restrict__ w1,
                             const float* __restrict__ g, const float* __restrict__ b,
                             unsigned short* __restrict__ O)
{
    __shared__ float wl[576];
    __shared__ float sg[64], sb[64];
    int tid = threadIdx.x;
    if (tid < 64) { sg[tid] = g[tid]*RSQ; sb[tid] = b[tid]; }
    for (int i = tid; i < 576; i += 256) wl[i] = w1[i];
    __syncthreads();
    int px = blockIdx.x*256 + tid;
    int n = blockIdx.z;
    if (px >= 15903) return;
    int h = px / 513, w = px - h*513;
    const float* xp = xm + (size_t)n*15903;
    float v[9];
    #pragma unroll
    for (int dh = 0; dh < 3; ++dh)
      #pragma unroll
      for (int dw = 0; dw < 3; ++dw) {
        int hh = h+dh-1, ww = w+dw-1;
        bool ok = ((unsigned)hh < 31u) && ((unsigned)ww < 513u);
        v[dh*3+dw] = ok ? xp[hh*513 + ww] : 0.f;
      }
    unsigned short* op = O + ((size_t)n*15903 + px)*64;
    #pragma unroll
    for (int c8 = 0; c8 < 8; ++c8) {
        unsigned tmp[8];
        #pragma unroll
        for (int j = 0; j < 8; ++j) {
            int co = c8*8 + j;
            const float* wr = &wl[co*9];
            float a = 0.f;
            #pragma unroll
            for (int t2 = 0; t2 < 9; ++t2) a += wr[t2]*v[t2];
            a = a*sg[co] + sb[co];
            a = (a >= 0.f) ? a : SLOPE*a;
            tmp[j] = f2bf(a);
        }
        uint4 pk;
        pk.x = tmp[0] | (tmp[1]<<16);
        pk.y = tmp[2] | (tmp[3]<<16);
        pk.z = tmp[4] | (tmp[5]<<16);
        pk.w = tmp[6] | (tmp[7]<<16);
        *(uint4*)(op + c8*8) = pk;
    }
}

// ---------------- implicit-GEMM 3x3 conv (+fused 1x1 shortcut) via MFMA ----------------
__launch_bounds__(256)
__global__ void conv_mfma_kernel(const unsigned short* __restrict__ X,
                                 const unsigned short* __restrict__ W9,
                                 const unsigned short* __restrict__ Xs,
                                 const unsigned short* __restrict__ Ws,
                                 unsigned short* __restrict__ O,
                                 int H, int W, int Cin, int Cs, int Cout,
                                 const float* __restrict__ g, const float* __restrict__ b)
{
    const int HW = H * W;
    const int lane = threadIdx.x & 63;
    const int wave = threadIdx.x >> 6;
    const int co64 = blockIdx.y * 64 + wave * 16;
    const int n = blockIdx.z;
    const int px0 = blockIdx.x * 64;
    const int l15 = lane & 15;
    const int kl = (lane >> 4) * 8;
    const short8 zf = {0,0,0,0,0,0,0,0};

    int hh_[4], ww_[4]; bool pv[4];
    #pragma unroll
    for (int t = 0; t < 4; ++t) {
        int px = px0 + t*16 + l15;
        pv[t] = px < HW;
        int pc = pv[t] ? px : 0;
        hh_[t] = pc / W;
        ww_[t] = pc - hh_[t]*W;
    }

    const unsigned short* Xn = X + (size_t)n * HW * Cin;
    f32x4 acc0 = {0,0,0,0}, acc1 = {0,0,0,0}, acc2 = {0,0,0,0}, acc3 = {0,0,0,0};

    for (int tap = 0; tap < 9; ++tap) {
        int dh = tap/3 - 1, dw = tap - (tap/3)*3 - 1;
        const short8* ap = (const short8*)(W9 + ((size_t)tap*Cout + co64 + l15)*Cin + kl);
        const short8* bp[4]; bool v[4];
        #pragma unroll
        for (int t = 0; t < 4; ++t) {
            int hh = hh_[t] + dh, ww = ww_[t] + dw;
            v[t] = pv[t] && ((unsigned)hh < (unsigned)H) && ((unsigned)ww < (unsigned)W);
            int p2 = v[t] ? (hh*W + ww) : 0;
            bp[t] = (const short8*)(Xn + (size_t)p2*Cin + kl);
        }
        for (int k0 = 0; k0 < Cin; k0 += 32) {
            int ko = k0 >> 3;
            short8 a  = ap[ko];
            short8 b0 = v[0] ? bp[0][ko] : zf;
            short8 b1 = v[1] ? bp[1][ko] : zf;
            short8 b2 = v[2] ? bp[2][ko] : zf;
            short8 b3 = v[3] ? bp[3][ko] : zf;
            acc0 = __builtin_amdgcn_mfma_f32_16x16x32_bf16(a, b0, acc0, 0, 0, 0);
            acc1 = __builtin_amdgcn_mfma_f32_16x16x32_bf16(a, b1, acc1, 0, 0, 0);
            acc2 = __builtin_amdgcn_mfma_f32_16x16x32_bf16(a, b2, acc2, 0, 0, 0);
            acc3 = __builtin_amdgcn_mfma_f32_16x16x32_bf16(a, b3, acc3, 0, 0, 0);
        }
    }

    if (Ws) {
        const unsigned short* X2n = Xs + (size_t)n * HW * Cs;
        const short8* ap = (const short8*)(Ws + ((size_t)(co64 + l15))*Cs + kl);
        const short8* bp[4];
        #pragma unroll
        for (int t = 0; t < 4; ++t) {
            int p2 = pv[t] ? (hh_[t]*W + ww_[t]) : 0;
            bp[t] = (const short8*)(X2n + (size_t)p2*Cs + kl);
        }
        for (int k0 = 0; k0 < Cs; k0 += 32) {
            int ko = k0 >> 3;
            short8 a  = ap[ko];
            short8 b0 = pv[0] ? bp[0][ko] : zf;
            short8 b1 = pv[1] ? bp[1][ko] : zf;
            short8 b2 = pv[2] ? bp[2][ko] : zf;
            short8 b3 = pv[3] ? bp[3][ko] : zf;
            acc0 = __builtin_amdgcn_mfma_f32_16x16x32_bf16(a, b0, acc0, 0, 0, 0);
            acc1 = __builtin_amdgcn_mfma_f32_16x16x32_bf16(a, b1, acc1, 0, 0, 0);
            acc2 = __builtin_amdgcn_mfma_f32_16x16x32_bf16(a, b2, acc2, 0, 0, 0);
            acc3 = __builtin_amdgcn_mfma_f32_16x16x32_bf16(a, b3, acc3, 0, 0, 0);
        }
    }

    int cb = co64 + (lane >> 4)*4;
    float s0 = g[cb+0]*RSQ, s1 = g[cb+1]*RSQ, s2 = g[cb+2]*RSQ, s3 = g[cb+3]*RSQ;
    float o0 = b[cb+0], o1 = b[cb+1], o2 = b[cb+2], o3 = b[cb+3];

#define EPI(ACC, T) do { \
    if (pv[T]) { \
        int px = px0 + (T)*16 + l15; \
        float v0 = ACC[0]*s0 + o0; v0 = (v0 >= 0.f) ? v0 : SLOPE*v0; \
        float v1 = ACC[1]*s1 + o1; v1 = (v1 >= 0.f) ? v1 : SLOPE*v1; \
        float v2 = ACC[2]*s2 + o2; v2 = (v2 >= 0.f) ? v2 : SLOPE*v2; \
        float v3 = ACC[3]*s3 + o3; v3 = (v3 >= 0.f) ? v3 : SLOPE*v3; \
        uint2 pk; \
        pk.x = (unsigned)f2bf(v0) | ((unsigned)f2bf(v1) << 16); \
        pk.y = (unsigned)f2bf(v2) | ((unsigned)f2bf(v3) << 16); \
        *(uint2*)(O + ((size_t)n*HW + px)*Cout + cb) = pk; \
    } \
} while(0)
    EPI(acc0, 0); EPI(acc1, 1); EPI(acc2, 2); EPI(acc3, 3);
#undef EPI
}

// ---------------- maxpool(1,4) VALID on NHWC bf16 ----------------
__global__ void pool_nhwc_kernel(const unsigned short* __restrict__ in,
                                 unsigned short* __restrict__ out,
                                 int W, int Wout, int C, int total8)
{
    int idx = blockIdx.x*256 + threadIdx.x;
    if (idx >= total8) return;
    int c8 = idx % (C >> 3);
    int r = idx / (C >> 3);
    int w = r % Wout;
    int nh = r / Wout;
    const unsigned short* ip = in + (((size_t)nh*W) + (size_t)w*4)*C + c8*8;
    float m0=-1e30f,m1=-1e30f,m2=-1e30f,m3=-1e30f,m4=-1e30f,m5=-1e30f,m6=-1e30f,m7=-1e30f;
    #pragma unroll
    for (int i = 0; i < 4; ++i) {
        uint4 u = *(const uint4*)(ip + (size_t)i*C);
        m0 = fmaxf(m0, bf2f((unsigned short)(u.x & 0xffff)));
        m1 = fmaxf(m1, bf2f((unsigned short)(u.x >> 16)));
        m2 = fmaxf(m2, bf2f((unsigned short)(u.y & 0xffff)));
        m3 = fmaxf(m3, bf2f((unsigned short)(u.y >> 16)));
        m4 = fmaxf(m4, bf2f((unsigned short)(u.z & 0xffff)));
        m5 = fmaxf(m5, bf2f((unsigned short)(u.z >> 16)));
        m6 = fmaxf(m6, bf2f((unsigned short)(u.w & 0xffff)));
        m7 = fmaxf(m7, bf2f((unsigned short)(u.w >> 16)));
    }
    uint4 ov;
    ov.x = (unsigned)f2bf(m0) | ((unsigned)f2bf(m1) << 16);
    ov.y = (unsigned)f2bf(m2) | ((unsigned)f2bf(m3) << 16);
    ov.z = (unsigned)f2bf(m4) | ((unsigned)f2bf(m5) << 16);
    ov.w = (unsigned)f2bf(m6) | ((unsigned)f2bf(m7) << 16);
    *(uint4*)(out + (size_t)idx*8) = ov;
}

// ---------------- feats: [n][31][2][256] bf16 NHWC -> [n][31][512] fp32 ----------------
__global__ void feats_kernel(const unsigned short* __restrict__ p4, float* __restrict__ fe)
{
    int idx = blockIdx.x*256 + threadIdx.x;   // 507904
    int cw = idx & 511;
    int nh = idx >> 9;
    int c = cw >> 1, w = cw & 1;
    fe[idx] = bf2f(p4[((size_t)nh*2 + w)*256 + c]);
}

// ---------------- tiled SGEMM: C[M,N] = A[M,K] @ B[N,K]^T + bias(+bias2) ----------------
// XPOSE=1: store C[((m%31)*N + n)*32 + m/31]  (xp layout [t][j][b], M = b*31+t)
#define GM 32
#define GN 64
#define GK 32
template<int XPOSE>
__launch_bounds__(256)
__global__ void gemm_bias_kernel(const float* __restrict__ A, const float* __restrict__ B,
                                 const float* __restrict__ bias, const float* __restrict__ bias2,
                                 float* __restrict__ C, int M, int N, int K)
{
    __shared__ float As[GM][GK+1];
    __shared__ float Bs[GN][GK+1];
    int m0 = blockIdx.x*GM, n0 = blockIdx.y*GN;
    int tid = threadIdx.x;
    int mi = tid >> 4;
    int ni = (tid & 15) * 4;
    float acc[2][4] = {};

    for (int k0 = 0; k0 < K; k0 += GK) {
        for (int i = tid; i < GM*GK; i += 256) {
            int r = i >> 5, c = i & 31;
            int m = m0 + r;
            As[r][c] = (m < M) ? A[(size_t)m*K + k0 + c] : 0.f;
        }
        for (int i = tid; i < GN*GK; i += 256) {
            int r = i >> 5, c = i & 31;
            int n = n0 + r;
            Bs[r][c] = (n < N) ? B[(size_t)n*K + k0 + c] : 0.f;
        }
        __syncthreads();
        #pragma unroll
        for (int kk = 0; kk < GK; ++kk) {
            float a0 = As[mi][kk], a1 = As[mi+16][kk];
            float b0 = Bs[ni][kk], b1 = Bs[ni+1][kk], b2 = Bs[ni+2][kk], b3 = Bs[ni+3][kk];
            acc[0][0] += a0*b0; acc[0][1] += a0*b1; acc[0][2] += a0*b2; acc[0][3] += a0*b3;
            acc[1][0] += a1*b0; acc[1][1] += a1*b1; acc[1][2] += a1*b2; acc[1][3] += a1*b3;
        }
        __syncthreads();
    }
    #pragma unroll
    for (int r = 0; r < 2; ++r) {
        int m = m0 + mi + r*16;
        if (m >= M) continue;
        #pragma unroll
        for (int q = 0; q < 4; ++q) {
            int n = n0 + ni + q;
            if (n >= N) continue;
            float v = acc[r][q];
            if (bias)  v += bias[n];
            if (bias2) v += bias2[n];
            if (XPOSE) C[((size_t)(m % 31)*N + n)*32 + (m / 31)] = v;
            else       C[(size_t)m*N + n] = v;
        }
    }
}

// ---------------- LSTM scan via MFMA: 2 blocks (one per direction), 1024 thr ----------------
// xpT: [d][t][j=1024][b=32] fp32 (incl. both biases)
// wf:  [d][g][u0][kc][lane][8] bf16 fragments of whh
// hcat: [b][t][512] fp32; dir d -> cols d*256..
// h LDS layout: byte addr = (b*512 + k*2) ^ ((b&7)<<4)  -- SAME involution on write & read
__launch_bounds__(1024)
__global__ void lstm_scan_mfma(const float* __restrict__ xpT,
                               const unsigned short* __restrict__ wf,
                               float* __restrict__ hcat)
{
    const int d = blockIdx.x;
    const int tid = threadIdx.x;
    const int u0 = tid >> 6;          // wave id = u-group
    const int lane = tid & 63;
    const int l15 = lane & 15;
    const int q = lane >> 4;

    __shared__ unsigned short hbuf[2][8192];   // [buf][b*256 + k] bf16, XOR-swizzled

    ((int4*)hbuf[0])[tid] = make_int4(0,0,0,0);  // zero buf0 (16 KB)
    __syncthreads();

    const unsigned short* wfd = wf + (size_t)d*262144;
    const float* xpd = xpT + (size_t)d*992*1024;

    float c00=0.f,c01=0.f,c02=0.f,c03=0.f;   // c for bt=0, r=0..3
    float c10=0.f,c11=0.f,c12=0.f,c13=0.f;   // c for bt=1
    const int ubase = u0*16 + q*4;
    const int b0i = l15, b1i = 16 + l15;
    const int rb0 = b0i*512 + q*16;     // un-swizzled base (bytes)
    const int rb1 = b1i*512 + q*16;
    const int xr0 = (b0i&7)<<4;         // swizzle masks
    const int xr1 = (b1i&7)<<4;

    for (int s = 0; s < 31; ++s) {
        const int t = d ? (30 - s) : s;
        const int cur = s & 1, nxt = cur ^ 1;
        const float* xt = xpd + (size_t)t*32768;   // [j][b]

        // prefetch xp for this step's (b,u) cells (overlaps the MFMA loop)
        float xi0[4], xf0[4], xg0[4], xo0[4], xi1[4], xf1[4], xg1[4], xo1[4];
        #pragma unroll
        for (int r = 0; r < 4; ++r) {
            int u = ubase + r;
            xi0[r] = xt[(u      )*32 + b0i];  xi1[r] = xt[(u      )*32 + b1i];
            xf0[r] = xt[(u + 256)*32 + b0i];  xf1[r] = xt[(u + 256)*32 + b1i];
            xg0[r] = xt[(u + 512)*32 + b0i];  xg1[r] = xt[(u + 512)*32 + b1i];
            xo0[r] = xt[(u + 768)*32 + b0i];  xo1[r] = xt[(u + 768)*32 + b1i];
        }

        f32x4 a00={0,0,0,0}, a01={0,0,0,0}, a02={0,0,0,0}, a03={0,0,0,0};
        f32x4 a10={0,0,0,0}, a11={0,0,0,0}, a12={0,0,0,0}, a13={0,0,0,0};
        const char* hb = (const char*)hbuf[cur];
        #pragma unroll
        for (int kc = 0; kc < 8; ++kc) {
            const size_t wo = ((size_t)u0*8 + kc)*512 + (size_t)lane*8;
            short8 w0 = *(const short8*)(wfd + wo);            // gate i (g=0)
            short8 w1 = *(const short8*)(wfd + wo + 65536);    // f
            short8 w2 = *(const short8*)(wfd + wo + 131072);   // g
            short8 w3 = *(const short8*)(wfd + wo + 196608);   // o
            short8 h0 = *(const short8*)(hb + ((rb0 + kc*64) ^ xr0));  // FIXED: XOR after full offset
            short8 h1 = *(const short8*)(hb + ((rb1 + kc*64) ^ xr1));
            a00 = __builtin_amdgcn_mfma_f32_16x16x32_bf16(w0, h0, a00, 0, 0, 0);
            a01 = __builtin_amdgcn_mfma_f32_16x16x32_bf16(w1, h0, a01, 0, 0, 0);
            a02 = __builtin_amdgcn_mfma_f32_16x16x32_bf16(w2, h0, a02, 0, 0, 0);
            a03 = __builtin_amdgcn_mfma_f32_16x16x32_bf16(w3, h0, a03, 0, 0, 0);
            a10 = __builtin_amdgcn_mfma_f32_16x16x32_bf16(w0, h1, a10, 0, 0, 0);
            a11 = __builtin_amdgcn_mfma_f32_16x16x32_bf16(w1, h1, a11, 0, 0, 0);
            a12 = __builtin_amdgcn_mfma_f32_16x16x32_bf16(w2, h1, a12, 0, 0, 0);
            a13 = __builtin_amdgcn_mfma_f32_16x16x32_bf16(w3, h1, a13, 0, 0, 0);
        }

        char* hw = (char*)hbuf[nxt];
#define CELL(BT, AI, AF, AG, AO, C0, C1, C2, C3, XI, XF, XG, XO, BIDX) do { \
        float hv[4]; \
        { float gi=AI[0]+XI[0], gf=AF[0]+XF[0], gg=AG[0]+XG[0], go=AO[0]+XO[0]; \
          float cn = sigmoidf_(gf)*C0 + sigmoidf_(gi)*tanhf(gg); C0 = cn; hv[0] = sigmoidf_(go)*tanhf(cn); } \
        { float gi=AI[1]+XI[1], gf=AF[1]+XF[1], gg=AG[1]+XG[1], go=AO[1]+XO[1]; \
          float cn = sigmoidf_(gf)*C1 + sigmoidf_(gi)*tanhf(gg); C1 = cn; hv[1] = sigmoidf_(go)*tanhf(cn); } \
        { float gi=AI[2]+XI[2], gf=AF[2]+XF[2], gg=AG[2]+XG[2], go=AO[2]+XO[2]; \
          float cn = sigmoidf_(gf)*C2 + sigmoidf_(gi)*tanhf(gg); C2 = cn; hv[2] = sigmoidf_(go)*tanhf(cn); } \
        { float gi=AI[3]+XI[3], gf=AF[3]+XF[3], gg=AG[3]+XG[3], go=AO[3]+XO[3]; \
          float cn = sigmoidf_(gf)*C3 + sigmoidf_(gi)*tanhf(gg); C3 = cn; hv[3] = sigmoidf_(go)*tanhf(cn); } \
        short4 hp; \
        hp.x = (short)f2bf(hv[0]); hp.y = (short)f2bf(hv[1]); \
        hp.z = (short)f2bf(hv[2]); hp.w = (short)f2bf(hv[3]); \
        *(short4*)(hw + (((BIDX)*512 + ubase*2) ^ (((BIDX)&7)<<4))) = hp; \
        *(float4*)(&hcat[((size_t)(BIDX)*31 + t)*512 + (size_t)d*256 + ubase]) = \
            make_float4(hv[0], hv[1], hv[2], hv[3]); \
} while(0)
        CELL(0, a00, a01, a02, a03, c00, c01, c02, c03, xi0, xf0, xg0, xo0, b0i);
        CELL(1, a10, a11, a12, a13, c10, c11, c12, c13, xi1, xf1, xg1, xo1, b1i);
#undef CELL
        __syncthreads();
    }
}

extern "C" void kernel_launch(void* const* d_in, const int* in_sizes, int n_in,
                              void* d_out, int out_size, void* d_ws, size_t ws_size,
                              hipStream_t stream)
{
    const float* x    = (const float*)d_in[0];
    const float* fW   = (const float*)d_in[1];
    const float* fB   = (const float*)d_in[2];
    const float* cbw1 = (const float*)d_in[3];
    const float* cbg  = (const float*)d_in[4];
    const float* cbb  = (const float*)d_in[5];
    const float* cbw2 = (const float*)d_in[6];
    const float* r1pg = (const float*)d_in[7];
    const float* r1pb = (const float*)d_in[8];
    const float* r1wA = (const float*)d_in[9];
    const float* r1g  = (const float*)d_in[10];
    const float* r1b  = (const float*)d_in[11];
    const float* r1wB = (const float*)d_in[12];
    const float* r1s  = (const float*)d_in[13];
    const float* r2pg = (const float*)d_in[14];
    const float* r2pb = (const float*)d_in[15];
    const float* r2wA = (const float*)d_in[16];
    const float* r2g  = (const float*)d_in[17];
    const float* r2b  = (const float*)d_in[18];
    const float* r2wB = (const float*)d_in[19];
    const float* r2s  = (const float*)d_in[20];
    const float* r3pg = (const float*)d_in[21];
    const float* r3pb = (const float*)d_in[22];
    const float* r3wA = (const float*)d_in[23];
    const float* r3g  = (const float*)d_in[24];
    const float* r3b  = (const float*)d_in[25];
    const float* r3wB = (const float*)d_in[26];
    const float* r3s  = (const float*)d_in[27];
    const float* pbg  = (const float*)d_in[28];
    const float* pbb  = (const float*)d_in[29];
    const float* wih_f = (const float*)d_in[30];
    const float* whh_f = (const float*)d_in[31];
    const float* bih_f = (const float*)d_in[32];
    const float* bhh_f = (const float*)d_in[33];
    const float* wih_b = (const float*)d_in[34];
    const float* whh_b = (const float*)d_in[35];
    const float* bih_b = (const float*)d_in[36];
    const float* bhh_b = (const float*)d_in[37];
    const float* clsw  = (const float*)d_in[38];
    const float* clsb  = (const float*)d_in[39];
    float* out = (float*)d_out;
    float* ws  = (float*)d_ws;

    // ---- workspace sizing (floats) ----
    const size_t FIXEDF = 962560      // transformed conv weights
                        + 508896      // P
                        + 508896      // XM
                        + 253952      // XP4 (bf16)
                        + 507904      // FE
                        + 262144      // WF (2 x 262144 ushort)
                        + 2031616     // XPT (2 x 992x1024 fp32)
                        + 507904;     // HC
    const size_t PCF = 508896*2 + 126976 + 63488 + 23808;
    int NC = 0;
    const int cands[4] = {8,4,2,1};
    for (int i = 0; i < 4; ++i) {
        if ((FIXEDF + (size_t)cands[i]*PCF)*sizeof(float) <= ws_size) { NC = cands[i]; break; }
    }
    if (!NC) return;

    float* p = ws;
    unsigned short* WTR = (unsigned short*)p; p += 962560;
    float* P   = p; p += 508896;
    float* XM  = p; p += 508896;
    unsigned short* XP4 = (unsigned short*)p; p += 253952;
    float* FE  = p; p += 507904;
    unsigned short* WF = (unsigned short*)p; p += 262144;
    float* XPT = p; p += 2031616;
    float* HC  = p; p += 507904;
    unsigned short* REG1 = (unsigned short*)p; p += (size_t)NC*508896;
    unsigned short* REG2 = (unsigned short*)p; p += (size_t)NC*508896;
    unsigned short* XP1c = (unsigned short*)p; p += (size_t)NC*126976;
    unsigned short* XP2c = (unsigned short*)p; p += (size_t)NC*63488;
    unsigned short* XP3c = (unsigned short*)p; p += (size_t)NC*23808;

    unsigned short* w2T  = WTR + 0;
    unsigned short* r1AT = WTR + 36864;
    unsigned short* r1BT = WTR + 110592;
    unsigned short* r1ST = WTR + 258048;
    unsigned short* r2AT = WTR + 266240;
    unsigned short* r2BT = WTR + 487424;
    unsigned short* r2ST = WTR + 819200;
    unsigned short* r3AT = WTR + 843776;
    unsigned short* r3BT = WTR + 1286144;
    unsigned short* r3ST = WTR + 1875968;

    auto cdiv = [](int a, int b){ return (a + b - 1) / b; };

    // ---- weight transforms ----
    wtrans9_kernel<<<cdiv(9*64*64,256),   256, 0, stream>>>(cbw2, w2T, 64, 64);
    wtrans9_kernel<<<cdiv(9*128*64,256),  256, 0, stream>>>(r1wA, r1AT, 128, 64);
    wtrans9_kernel<<<cdiv(9*128*128,256), 256, 0, stream>>>(r1wB, r1BT, 128, 128);
    wtrans1_kernel<<<cdiv(128*64,256),    256, 0, stream>>>(r1s, r1ST, 128*64);
    wtrans9_kernel<<<cdiv(9*192*128,256), 256, 0, stream>>>(r2wA, r2AT, 192, 128);
    wtrans9_kernel<<<cdiv(9*192*192,256), 256, 0, stream>>>(r2wB, r2BT, 192, 192);
    wtrans1_kernel<<<cdiv(192*128,256),   256, 0, stream>>>(r2s, r2ST, 192*128);
    wtrans9_kernel<<<cdiv(9*256*192,256), 256, 0, stream>>>(r3wA, r3AT, 256, 192);
    wtrans9_kernel<<<cdiv(9*256*256,256), 256, 0, stream>>>(r3wB, r3BT, 256, 256);
    wtrans1_kernel<<<cdiv(256*192,256),   256, 0, stream>>>(r3s, r3ST, 256*192);
    whh_frag_kernel<<<1024, 256, 0, stream>>>(whh_f, WF);
    whh_frag_kernel<<<1024, 256, 0, stream>>>(whh_b, WF + 262144);

    // ---- frontend mask ----
    mask_partial_kernel<<<dim3(63, 32), 256, 0, stream>>>(fW, fB, P);
    mask_finalize_apply<<<63, 256, 0, stream>>>(P, x, XM);

    // ---- conv stack, chunked over batch ----
    for (int c0 = 0; c0 < 32; c0 += NC) {
        const float* xmc = XM + (size_t)c0*15903;
        conv1_kernel<<<dim3(63, 1, NC), 256, 0, stream>>>(xmc, cbw1, cbg, cbb, REG1);
        conv_mfma_kernel<<<dim3(cdiv(15903,64), 1, NC), 256, 0, stream>>>(
            REG1, w2T, nullptr, nullptr, REG2, 31, 513, 64, 0, 64, r1pg, r1pb);
        pool_nhwc_kernel<<<cdiv(NC*31*128*8,256), 256, 0, stream>>>(REG2, XP1c, 513, 128, 64, NC*31*128*8);
        conv_mfma_kernel<<<dim3(cdiv(31*128,64), 2, NC), 256, 0, stream>>>(
            XP1c, r1AT, nullptr, nullptr, REG1, 31, 128, 64, 0, 128, r1g, r1b);
        conv_mfma_kernel<<<dim3(cdiv(31*128,64), 2, NC), 256, 0, stream>>>(
            REG1, r1BT, XP1c, r1ST, REG2, 31, 128, 128, 64, 128, r2pg, r2pb);
        pool_nhwc_kernel<<<cdiv(NC*31*32*16,256), 256, 0, stream>>>(REG2, XP2c, 128, 32, 128, NC*31*32*16);
        conv_mfma_kernel<<<dim3(cdiv(31*32,64), 3, NC), 256, 0, stream>>>(
            XP2c, r2AT, nullptr, nullptr, REG1, 31, 32, 128, 0, 192, r2g, r2b);
        conv_mfma_kernel<<<dim3(cdiv(31*32,64), 3, NC), 256, 0, stream>>>(
            REG1, r2BT, XP2c, r2ST, REG2, 31, 32, 192, 128, 192, r3pg, r3pb);
        pool_nhwc_kernel<<<cdiv(NC*31*8*24,256), 256, 0, stream>>>(REG2, XP3c, 32, 8, 192, NC*31*8*24);
        conv_mfma_kernel<<<dim3(cdiv(31*8,64), 4, NC), 256, 0, stream>>>(
            XP3c, r3AT, nullptr, nullptr, REG1, 31, 8, 192, 0, 256, r3g, r3b);
        conv_mfma_kernel<<<dim3(cdiv(31*8,64), 4, NC), 256, 0, stream>>>(
            REG1, r3BT, XP3c, r3ST, REG2, 31, 8, 256, 192, 256, pbg, pbb);
        pool_nhwc_kernel<<<cdiv(NC*31*2*32,256), 256, 0, stream>>>(
            REG2, XP4 + (size_t)c0*15872, 8, 2, 256, NC*31*2*32);
    }

    // feats (32,31,512) fp32
    feats_kernel<<<1984, 256, 0, stream>>>(XP4, FE);

    // LSTM input projections -> xpT [d][t][j][b]
    gemm_bias_kernel<1><<<dim3(31, 16), 256, 0, stream>>>(FE, wih_f, bih_f, bhh_f, XPT,           992, 1024, 512);
    gemm_bias_kernel<1><<<dim3(31, 16), 256, 0, stream>>>(FE, wih_b, bih_b, bhh_b, XPT + 1015808, 992, 1024, 512);

    // fused bidirectional scan (2 blocks, one per direction)
    lstm_scan_mfma<<<2, 1024, 0, stream>>>(XPT, WF, HC);

    // classifier -> d_out (32,31,722)
    gemm_bias_kernel<0><<<dim3(31, 12), 256, 0, stream>>>(HC, clsw, clsb, nullptr, out, 992, 722, 512);
}

// Round 6
// 1998.510 us; speedup vs baseline: 1.4050x; 1.4050x over previous
//
#include <hip/hip_runtime.h>
#include <hip/hip_bf16.h>
#include <math.h>

#define RSQ 0.99999500003749969f   // 1/sqrt(1+1e-5)
#define SLOPE 0.01f

typedef __attribute__((ext_vector_type(8))) short short8;
typedef __attribute__((ext_vector_type(4))) float f32x4;

__device__ __forceinline__ float sigmoidf_(float x){ return 1.0f/(1.0f+expf(-x)); }

__device__ __forceinline__ unsigned short f2bf(float f){
    unsigned u = __float_as_uint(f);
    u += 0x7fff + ((u >> 16) & 1);      // RNE
    return (unsigned short)(u >> 16);
}
__device__ __forceinline__ float bf2f(unsigned short s){
    return __uint_as_float(((unsigned)s) << 16);
}

// ---------------- mask: prod_k cos(fW*rng + fB) ----------------
__global__ void mask_partial_kernel(const float* __restrict__ fW, const float* __restrict__ fB,
                                    float* __restrict__ partial)
{
    int p = blockIdx.x*256 + threadIdx.x;   // 0..15902
    if (p >= 15903) return;
    int w = p % 513;
    float r = (float)(w + 1);
    int k0 = blockIdx.y * 32;
    float prod = 1.0f;
    for (int k = k0; k < k0 + 32; ++k) {
        float a = fW[(size_t)k*15903 + p] * r + fB[(size_t)k*15903 + p];
        prod *= cosf(a);
    }
    partial[blockIdx.y*15903 + p] = prod;
}

__global__ void mask_finalize_apply(const float* __restrict__ partial, const float* __restrict__ x,
                                    float* __restrict__ xm)
{
    int p = blockIdx.x*256 + threadIdx.x;
    if (p >= 15903) return;
    float m = 1.0f;
    #pragma unroll
    for (int c = 0; c < 32; ++c) m *= partial[c*15903 + p];
    for (int n = 0; n < 32; ++n)
        xm[(size_t)n*15903 + p] = x[(size_t)n*15903 + p] * m;
}

// ---------------- weight transforms ----------------
// OIHW fp32 -> [tap][co][ci] bf16
__global__ void wtrans9_kernel(const float* __restrict__ w, unsigned short* __restrict__ o,
                               int Cout, int Cin)
{
    int idx = blockIdx.x*256 + threadIdx.x;
    int cc = Cout*Cin;
    if (idx >= 9*cc) return;
    int tap = idx / cc;
    int r = idx - tap*cc;
    int co = r / Cin, ci = r - co*Cin;
    int kh = tap/3, kw = tap - kh*3;
    o[idx] = f2bf(w[((size_t)(co*Cin + ci)*3 + kh)*3 + kw]);
}
__global__ void wtrans1_kernel(const float* __restrict__ w, unsigned short* __restrict__ o, int total)
{
    int idx = blockIdx.x*256 + threadIdx.x;
    if (idx < total) o[idx] = f2bf(w[idx]);
}

// whh (1024,256) fp32 -> MFMA-fragment-contiguous bf16:
// out[g][u0][kc][lane][e], j = 256g + 16u0 + (lane&15), k = 32kc + 8(lane>>4) + e
__global__ void whh_frag_kernel(const float* __restrict__ whh, unsigned short* __restrict__ out)
{
    int tid = blockIdx.x*256 + threadIdx.x;  // 262144 exact
    int e    = tid & 7;
    int lane = (tid >> 3) & 63;
    int kc   = (tid >> 9) & 7;
    int u0   = (tid >> 12) & 15;
    int g    = tid >> 16;
    int j = (g << 8) + (u0 << 4) + (lane & 15);
    int k = (kc << 5) + ((lane >> 4) << 3) + e;
    out[tid] = f2bf(whh[(size_t)j*256 + k]);
}

// ---------------- conv1: Cin=1 direct, fp32 in -> bf16 NHWC out ----------------
__launch_bounds__(256)
__global__ void conv1_kernel(const float* __restrict__ xm, const float* __restrict__ w1,
                             const float* __restrict__ g, const float* __restrict__ b,
                             unsigned short* __restrict__ O)
{
    __shared__ float wl[576];
    __shared__ float sg[64], sb[64];
    int tid = threadIdx.x;
    if (tid < 64) { sg[tid] = g[tid]*RSQ; sb[tid] = b[tid]; }
    for (int i = tid; i < 576; i += 256) wl[i] = w1[i];
    __syncthreads();
    int px = blockIdx.x*256 + tid;
    int n = blockIdx.z;
    if (px >= 15903) return;
    int h = px / 513, w = px - h*513;
    const float* xp = xm + (size_t)n*15903;
    float v[9];
    #pragma unroll
    for (int dh = 0; dh < 3; ++dh)
      #pragma unroll
      for (int dw = 0; dw < 3; ++dw) {
        int hh = h+dh-1, ww = w+dw-1;
        bool ok = ((unsigned)hh < 31u) && ((unsigned)ww < 513u);
        v[dh*3+dw] = ok ? xp[hh*513 + ww] : 0.f;
      }
    unsigned short* op = O + ((size_t)n*15903 + px)*64;
    #pragma unroll
    for (int c8 = 0; c8 < 8; ++c8) {
        unsigned tmp[8];
        #pragma unroll
        for (int j = 0; j < 8; ++j) {
            int co = c8*8 + j;
            const float* wr = &wl[co*9];
            float a = 0.f;
            #pragma unroll
            for (int t2 = 0; t2 < 9; ++t2) a += wr[t2]*v[t2];
            a = a*sg[co] + sb[co];
            a = (a >= 0.f) ? a : SLOPE*a;
            tmp[j] = f2bf(a);
        }
        uint4 pk;
        pk.x = tmp[0] | (tmp[1]<<16);
        pk.y = tmp[2] | (tmp[3]<<16);
        pk.z = tmp[4] | (tmp[5]<<16);
        pk.w = tmp[6] | (tmp[7]<<16);
        *(uint4*)(op + c8*8) = pk;
    }
}

// ---------------- implicit-GEMM 3x3 conv (+fused 1x1 shortcut) via MFMA ----------------
__launch_bounds__(256)
__global__ void conv_mfma_kernel(const unsigned short* __restrict__ X,
                                 const unsigned short* __restrict__ W9,
                                 const unsigned short* __restrict__ Xs,
                                 const unsigned short* __restrict__ Ws,
                                 unsigned short* __restrict__ O,
                                 int H, int W, int Cin, int Cs, int Cout,
                                 const float* __restrict__ g, const float* __restrict__ b)
{
    const int HW = H * W;
    const int lane = threadIdx.x & 63;
    const int wave = threadIdx.x >> 6;
    const int co64 = blockIdx.y * 64 + wave * 16;
    const int n = blockIdx.z;
    const int px0 = blockIdx.x * 64;
    const int l15 = lane & 15;
    const int kl = (lane >> 4) * 8;
    const short8 zf = {0,0,0,0,0,0,0,0};

    int hh_[4], ww_[4]; bool pv[4];
    #pragma unroll
    for (int t = 0; t < 4; ++t) {
        int px = px0 + t*16 + l15;
        pv[t] = px < HW;
        int pc = pv[t] ? px : 0;
        hh_[t] = pc / W;
        ww_[t] = pc - hh_[t]*W;
    }

    const unsigned short* Xn = X + (size_t)n * HW * Cin;
    f32x4 acc0 = {0,0,0,0}, acc1 = {0,0,0,0}, acc2 = {0,0,0,0}, acc3 = {0,0,0,0};

    for (int tap = 0; tap < 9; ++tap) {
        int dh = tap/3 - 1, dw = tap - (tap/3)*3 - 1;
        const short8* ap = (const short8*)(W9 + ((size_t)tap*Cout + co64 + l15)*Cin + kl);
        const short8* bp[4]; bool v[4];
        #pragma unroll
        for (int t = 0; t < 4; ++t) {
            int hh = hh_[t] + dh, ww = ww_[t] + dw;
            v[t] = pv[t] && ((unsigned)hh < (unsigned)H) && ((unsigned)ww < (unsigned)W);
            int p2 = v[t] ? (hh*W + ww) : 0;
            bp[t] = (const short8*)(Xn + (size_t)p2*Cin + kl);
        }
        for (int k0 = 0; k0 < Cin; k0 += 32) {
            int ko = k0 >> 3;
            short8 a  = ap[ko];
            short8 b0 = v[0] ? bp[0][ko] : zf;
            short8 b1 = v[1] ? bp[1][ko] : zf;
            short8 b2 = v[2] ? bp[2][ko] : zf;
            short8 b3 = v[3] ? bp[3][ko] : zf;
            acc0 = __builtin_amdgcn_mfma_f32_16x16x32_bf16(a, b0, acc0, 0, 0, 0);
            acc1 = __builtin_amdgcn_mfma_f32_16x16x32_bf16(a, b1, acc1, 0, 0, 0);
            acc2 = __builtin_amdgcn_mfma_f32_16x16x32_bf16(a, b2, acc2, 0, 0, 0);
            acc3 = __builtin_amdgcn_mfma_f32_16x16x32_bf16(a, b3, acc3, 0, 0, 0);
        }
    }

    if (Ws) {
        const unsigned short* X2n = Xs + (size_t)n * HW * Cs;
        const short8* ap = (const short8*)(Ws + ((size_t)(co64 + l15))*Cs + kl);
        const short8* bp[4];
        #pragma unroll
        for (int t = 0; t < 4; ++t) {
            int p2 = pv[t] ? (hh_[t]*W + ww_[t]) : 0;
            bp[t] = (const short8*)(X2n + (size_t)p2*Cs + kl);
        }
        for (int k0 = 0; k0 < Cs; k0 += 32) {
            int ko = k0 >> 3;
            short8 a  = ap[ko];
            short8 b0 = pv[0] ? bp[0][ko] : zf;
            short8 b1 = pv[1] ? bp[1][ko] : zf;
            short8 b2 = pv[2] ? bp[2][ko] : zf;
            short8 b3 = pv[3] ? bp[3][ko] : zf;
            acc0 = __builtin_amdgcn_mfma_f32_16x16x32_bf16(a, b0, acc0, 0, 0, 0);
            acc1 = __builtin_amdgcn_mfma_f32_16x16x32_bf16(a, b1, acc1, 0, 0, 0);
            acc2 = __builtin_amdgcn_mfma_f32_16x16x32_bf16(a, b2, acc2, 0, 0, 0);
            acc3 = __builtin_amdgcn_mfma_f32_16x16x32_bf16(a, b3, acc3, 0, 0, 0);
        }
    }

    int cb = co64 + (lane >> 4)*4;
    float s0 = g[cb+0]*RSQ, s1 = g[cb+1]*RSQ, s2 = g[cb+2]*RSQ, s3 = g[cb+3]*RSQ;
    float o0 = b[cb+0], o1 = b[cb+1], o2 = b[cb+2], o3 = b[cb+3];

#define EPI(ACC, T) do { \
    if (pv[T]) { \
        int px = px0 + (T)*16 + l15; \
        float v0 = ACC[0]*s0 + o0; v0 = (v0 >= 0.f) ? v0 : SLOPE*v0; \
        float v1 = ACC[1]*s1 + o1; v1 = (v1 >= 0.f) ? v1 : SLOPE*v1; \
        float v2 = ACC[2]*s2 + o2; v2 = (v2 >= 0.f) ? v2 : SLOPE*v2; \
        float v3 = ACC[3]*s3 + o3; v3 = (v3 >= 0.f) ? v3 : SLOPE*v3; \
        uint2 pk; \
        pk.x = (unsigned)f2bf(v0) | ((unsigned)f2bf(v1) << 16); \
        pk.y = (unsigned)f2bf(v2) | ((unsigned)f2bf(v3) << 16); \
        *(uint2*)(O + ((size_t)n*HW + px)*Cout + cb) = pk; \
    } \
} while(0)
    EPI(acc0, 0); EPI(acc1, 1); EPI(acc2, 2); EPI(acc3, 3);
#undef EPI
}

// ---------------- maxpool(1,4) VALID on NHWC bf16 ----------------
__global__ void pool_nhwc_kernel(const unsigned short* __restrict__ in,
                                 unsigned short* __restrict__ out,
                                 int W, int Wout, int C, int total8)
{
    int idx = blockIdx.x*256 + threadIdx.x;
    if (idx >= total8) return;
    int c8 = idx % (C >> 3);
    int r = idx / (C >> 3);
    int w = r % Wout;
    int nh = r / Wout;
    const unsigned short* ip = in + (((size_t)nh*W) + (size_t)w*4)*C + c8*8;
    float m0=-1e30f,m1=-1e30f,m2=-1e30f,m3=-1e30f,m4=-1e30f,m5=-1e30f,m6=-1e30f,m7=-1e30f;
    #pragma unroll
    for (int i = 0; i < 4; ++i) {
        uint4 u = *(const uint4*)(ip + (size_t)i*C);
        m0 = fmaxf(m0, bf2f((unsigned short)(u.x & 0xffff)));
        m1 = fmaxf(m1, bf2f((unsigned short)(u.x >> 16)));
        m2 = fmaxf(m2, bf2f((unsigned short)(u.y & 0xffff)));
        m3 = fmaxf(m3, bf2f((unsigned short)(u.y >> 16)));
        m4 = fmaxf(m4, bf2f((unsigned short)(u.z & 0xffff)));
        m5 = fmaxf(m5, bf2f((unsigned short)(u.z >> 16)));
        m6 = fmaxf(m6, bf2f((unsigned short)(u.w & 0xffff)));
        m7 = fmaxf(m7, bf2f((unsigned short)(u.w >> 16)));
    }
    uint4 ov;
    ov.x = (unsigned)f2bf(m0) | ((unsigned)f2bf(m1) << 16);
    ov.y = (unsigned)f2bf(m2) | ((unsigned)f2bf(m3) << 16);
    ov.z = (unsigned)f2bf(m4) | ((unsigned)f2bf(m5) << 16);
    ov.w = (unsigned)f2bf(m6) | ((unsigned)f2bf(m7) << 16);
    *(uint4*)(out + (size_t)idx*8) = ov;
}

// ---------------- feats: [n][31][2][256] bf16 NHWC -> [n][31][512] fp32 ----------------
__global__ void feats_kernel(const unsigned short* __restrict__ p4, float* __restrict__ fe)
{
    int idx = blockIdx.x*256 + threadIdx.x;   // 507904
    int cw = idx & 511;
    int nh = idx >> 9;
    int c = cw >> 1, w = cw & 1;
    fe[idx] = bf2f(p4[((size_t)nh*2 + w)*256 + c]);
}

// ---------------- tiled SGEMM: C[M,N] = A[M,K] @ B[N,K]^T + bias(+bias2) ----------------
// XPOSE=1: store C[((m%31)*32 + m/31)*N + n]  (xp layout [t][b][j], M = b*31+t)
#define GM 32
#define GN 64
#define GK 32
template<int XPOSE>
__launch_bounds__(256)
__global__ void gemm_bias_kernel(const float* __restrict__ A, const float* __restrict__ B,
                                 const float* __restrict__ bias, const float* __restrict__ bias2,
                                 float* __restrict__ C, int M, int N, int K)
{
    __shared__ float As[GM][GK+1];
    __shared__ float Bs[GN][GK+1];
    int m0 = blockIdx.x*GM, n0 = blockIdx.y*GN;
    int tid = threadIdx.x;
    int mi = tid >> 4;
    int ni = (tid & 15) * 4;
    float acc[2][4] = {};

    for (int k0 = 0; k0 < K; k0 += GK) {
        for (int i = tid; i < GM*GK; i += 256) {
            int r = i >> 5, c = i & 31;
            int m = m0 + r;
            As[r][c] = (m < M) ? A[(size_t)m*K + k0 + c] : 0.f;
        }
        for (int i = tid; i < GN*GK; i += 256) {
            int r = i >> 5, c = i & 31;
            int n = n0 + r;
            Bs[r][c] = (n < N) ? B[(size_t)n*K + k0 + c] : 0.f;
        }
        __syncthreads();
        #pragma unroll
        for (int kk = 0; kk < GK; ++kk) {
            float a0 = As[mi][kk], a1 = As[mi+16][kk];
            float b0 = Bs[ni][kk], b1 = Bs[ni+1][kk], b2 = Bs[ni+2][kk], b3 = Bs[ni+3][kk];
            acc[0][0] += a0*b0; acc[0][1] += a0*b1; acc[0][2] += a0*b2; acc[0][3] += a0*b3;
            acc[1][0] += a1*b0; acc[1][1] += a1*b1; acc[1][2] += a1*b2; acc[1][3] += a1*b3;
        }
        __syncthreads();
    }
    #pragma unroll
    for (int r = 0; r < 2; ++r) {
        int m = m0 + mi + r*16;
        if (m >= M) continue;
        #pragma unroll
        for (int q = 0; q < 4; ++q) {
            int n = n0 + ni + q;
            if (n >= N) continue;
            float v = acc[r][q];
            if (bias)  v += bias[n];
            if (bias2) v += bias2[n];
            if (XPOSE) C[((size_t)(m % 31)*32 + (m / 31))*N + n] = v;
            else       C[(size_t)m*N + n] = v;
        }
    }
}

// ---------------- LSTM scan via MFMA: 4 blocks = (dir x batch-half), 1024 thr ----------------
// xpT: [d][t][b=32][j=1024] fp32 (incl. both biases)
// wf:  [d][g][u0][kc][lane][8] bf16 fragments of whh
// hcat: [b][t][512] fp32; dir d -> cols d*256..
// h LDS layout (16 local batches): byte = (bl*512 + k*2) ^ ((bl&7)<<4) -- same involution both sides
__launch_bounds__(1024, 4)
__global__ void lstm_scan_mfma(const float* __restrict__ xpT,
                               const unsigned short* __restrict__ wf,
                               float* __restrict__ hcat)
{
    const int d  = blockIdx.x >> 1;
    const int bh = blockIdx.x & 1;
    const int tid = threadIdx.x;
    const int u0 = tid >> 6;          // wave id = u-group
    const int lane = tid & 63;
    const int l15 = lane & 15;
    const int q = lane >> 4;

    __shared__ unsigned short hbuf[2][4096];   // 2 x 8KB: [buf][bl*256 + k] bf16, swizzled

    ((int4*)hbuf)[tid] = make_int4(0,0,0,0);   // zero both buffers (16 KB total)
    __syncthreads();

    const unsigned short* wfd = wf + (size_t)d*262144;
    const float* xpd = xpT + (size_t)d*992*1024 + (size_t)bh*16*1024;  // batch-half base

    float c0=0.f, c1=0.f, c2=0.f, c3=0.f;      // cell state, u = ubase + r
    const int ubase = u0*16 + q*4;
    const int rb = l15*512 + q*16;             // un-swizzled h read base (bytes)
    const int xr = (l15&7)<<4;                 // swizzle mask
    const size_t wo0 = (size_t)u0*8*512 + (size_t)lane*8;

    for (int s = 0; s < 31; ++s) {
        const int t = d ? (30 - s) : s;
        const int cur = s & 1, nxt = cur ^ 1;
        const float* xb = xpd + (size_t)t*32768 + (size_t)l15*1024;   // this lane's batch row

        // vectorized xp prefetch: 4x float4 (i,f,g,o at u=ubase..ubase+3)
        float4 xi = *(const float4*)(xb + ubase);
        float4 xf = *(const float4*)(xb + 256 + ubase);
        float4 xg = *(const float4*)(xb + 512 + ubase);
        float4 xo = *(const float4*)(xb + 768 + ubase);

        f32x4 a0={0,0,0,0}, a1={0,0,0,0}, a2={0,0,0,0}, a3={0,0,0,0};
        const char* hb = (const char*)hbuf[cur];

        // wf double-buffered across kc (issue-early)
        short8 w0 = *(const short8*)(wfd + wo0);
        short8 w1 = *(const short8*)(wfd + wo0 + 65536);
        short8 w2 = *(const short8*)(wfd + wo0 + 131072);
        short8 w3 = *(const short8*)(wfd + wo0 + 196608);
        #pragma unroll
        for (int kc = 0; kc < 8; ++kc) {
            short8 n0, n1, n2, n3;
            if (kc < 7) {
                size_t wo = wo0 + (size_t)(kc+1)*512;
                n0 = *(const short8*)(wfd + wo);
                n1 = *(const short8*)(wfd + wo + 65536);
                n2 = *(const short8*)(wfd + wo + 131072);
                n3 = *(const short8*)(wfd + wo + 196608);
            }
            short8 h = *(const short8*)(hb + ((rb + kc*64) ^ xr));
            a0 = __builtin_amdgcn_mfma_f32_16x16x32_bf16(w0, h, a0, 0, 0, 0);
            a1 = __builtin_amdgcn_mfma_f32_16x16x32_bf16(w1, h, a1, 0, 0, 0);
            a2 = __builtin_amdgcn_mfma_f32_16x16x32_bf16(w2, h, a2, 0, 0, 0);
            a3 = __builtin_amdgcn_mfma_f32_16x16x32_bf16(w3, h, a3, 0, 0, 0);
            if (kc < 7) { w0 = n0; w1 = n1; w2 = n2; w3 = n3; }
        }

        // cell update (all four gates for (u,b) live in this lane's reg slot r)
        float hv[4];
        {
            float gi=a0[0]+xi.x, gf=a1[0]+xf.x, gg=a2[0]+xg.x, go=a3[0]+xo.x;
            float cn = sigmoidf_(gf)*c0 + sigmoidf_(gi)*tanhf(gg); c0 = cn; hv[0] = sigmoidf_(go)*tanhf(cn);
        }
        {
            float gi=a0[1]+xi.y, gf=a1[1]+xf.y, gg=a2[1]+xg.y, go=a3[1]+xo.y;
            float cn = sigmoidf_(gf)*c1 + sigmoidf_(gi)*tanhf(gg); c1 = cn; hv[1] = sigmoidf_(go)*tanhf(cn);
        }
        {
            float gi=a0[2]+xi.z, gf=a1[2]+xf.z, gg=a2[2]+xg.z, go=a3[2]+xo.z;
            float cn = sigmoidf_(gf)*c2 + sigmoidf_(gi)*tanhf(gg); c2 = cn; hv[2] = sigmoidf_(go)*tanhf(cn);
        }
        {
            float gi=a0[3]+xi.w, gf=a1[3]+xf.w, gg=a2[3]+xg.w, go=a3[3]+xo.w;
            float cn = sigmoidf_(gf)*c3 + sigmoidf_(gi)*tanhf(gg); c3 = cn; hv[3] = sigmoidf_(go)*tanhf(cn);
        }

        short4 hp;
        hp.x = (short)f2bf(hv[0]); hp.y = (short)f2bf(hv[1]);
        hp.z = (short)f2bf(hv[2]); hp.w = (short)f2bf(hv[3]);
        *(short4*)((char*)hbuf[nxt] + ((l15*512 + ubase*2) ^ xr)) = hp;
        int bg = bh*16 + l15;
        *(float4*)(&hcat[((size_t)bg*31 + t)*512 + (size_t)d*256 + ubase]) =
            make_float4(hv[0], hv[1], hv[2], hv[3]);

        __syncthreads();
    }
}

extern "C" void kernel_launch(void* const* d_in, const int* in_sizes, int n_in,
                              void* d_out, int out_size, void* d_ws, size_t ws_size,
                              hipStream_t stream)
{
    const float* x    = (const float*)d_in[0];
    const float* fW   = (const float*)d_in[1];
    const float* fB   = (const float*)d_in[2];
    const float* cbw1 = (const float*)d_in[3];
    const float* cbg  = (const float*)d_in[4];
    const float* cbb  = (const float*)d_in[5];
    const float* cbw2 = (const float*)d_in[6];
    const float* r1pg = (const float*)d_in[7];
    const float* r1pb = (const float*)d_in[8];
    const float* r1wA = (const float*)d_in[9];
    const float* r1g  = (const float*)d_in[10];
    const float* r1b  = (const float*)d_in[11];
    const float* r1wB = (const float*)d_in[12];
    const float* r1s  = (const float*)d_in[13];
    const float* r2pg = (const float*)d_in[14];
    const float* r2pb = (const float*)d_in[15];
    const float* r2wA = (const float*)d_in[16];
    const float* r2g  = (const float*)d_in[17];
    const float* r2b  = (const float*)d_in[18];
    const float* r2wB = (const float*)d_in[19];
    const float* r2s  = (const float*)d_in[20];
    const float* r3pg = (const float*)d_in[21];
    const float* r3pb = (const float*)d_in[22];
    const float* r3wA = (const float*)d_in[23];
    const float* r3g  = (const float*)d_in[24];
    const float* r3b  = (const float*)d_in[25];
    const float* r3wB = (const float*)d_in[26];
    const float* r3s  = (const float*)d_in[27];
    const float* pbg  = (const float*)d_in[28];
    const float* pbb  = (const float*)d_in[29];
    const float* wih_f = (const float*)d_in[30];
    const float* whh_f = (const float*)d_in[31];
    const float* bih_f = (const float*)d_in[32];
    const float* bhh_f = (const float*)d_in[33];
    const float* wih_b = (const float*)d_in[34];
    const float* whh_b = (const float*)d_in[35];
    const float* bih_b = (const float*)d_in[36];
    const float* bhh_b = (const float*)d_in[37];
    const float* clsw  = (const float*)d_in[38];
    const float* clsb  = (const float*)d_in[39];
    float* out = (float*)d_out;
    float* ws  = (float*)d_ws;

    // ---- workspace sizing (floats) ----
    const size_t FIXEDF = 962560      // transformed conv weights
                        + 508896      // P
                        + 508896      // XM
                        + 253952      // XP4 (bf16)
                        + 507904      // FE
                        + 262144      // WF (2 x 262144 ushort)
                        + 2031616     // XPT (2 x 31x32x1024 fp32)
                        + 507904;     // HC
    const size_t PCF = 508896*2 + 126976 + 63488 + 23808;
    int NC = 0;
    const int cands[6] = {32,16,8,4,2,1};
    for (int i = 0; i < 6; ++i) {
        if ((FIXEDF + (size_t)cands[i]*PCF)*sizeof(float) <= ws_size) { NC = cands[i]; break; }
    }
    if (!NC) return;

    float* p = ws;
    unsigned short* WTR = (unsigned short*)p; p += 962560;
    float* P   = p; p += 508896;
    float* XM  = p; p += 508896;
    unsigned short* XP4 = (unsigned short*)p; p += 253952;
    float* FE  = p; p += 507904;
    unsigned short* WF = (unsigned short*)p; p += 262144;
    float* XPT = p; p += 2031616;
    float* HC  = p; p += 507904;
    unsigned short* REG1 = (unsigned short*)p; p += (size_t)NC*508896;
    unsigned short* REG2 = (unsigned short*)p; p += (size_t)NC*508896;
    unsigned short* XP1c = (unsigned short*)p; p += (size_t)NC*126976;
    unsigned short* XP2c = (unsigned short*)p; p += (size_t)NC*63488;
    unsigned short* XP3c = (unsigned short*)p; p += (size_t)NC*23808;

    unsigned short* w2T  = WTR + 0;
    unsigned short* r1AT = WTR + 36864;
    unsigned short* r1BT = WTR + 110592;
    unsigned short* r1ST = WTR + 258048;
    unsigned short* r2AT = WTR + 266240;
    unsigned short* r2BT = WTR + 487424;
    unsigned short* r2ST = WTR + 819200;
    unsigned short* r3AT = WTR + 843776;
    unsigned short* r3BT = WTR + 1286144;
    unsigned short* r3ST = WTR + 1875968;

    auto cdiv = [](int a, int b){ return (a + b - 1) / b; };

    // ---- weight transforms ----
    wtrans9_kernel<<<cdiv(9*64*64,256),   256, 0, stream>>>(cbw2, w2T, 64, 64);
    wtrans9_kernel<<<cdiv(9*128*64,256),  256, 0, stream>>>(r1wA, r1AT, 128, 64);
    wtrans9_kernel<<<cdiv(9*128*128,256), 256, 0, stream>>>(r1wB, r1BT, 128, 128);
    wtrans1_kernel<<<cdiv(128*64,256),    256, 0, stream>>>(r1s, r1ST, 128*64);
    wtrans9_kernel<<<cdiv(9*192*128,256), 256, 0, stream>>>(r2wA, r2AT, 192, 128);
    wtrans9_kernel<<<cdiv(9*192*192,256), 256, 0, stream>>>(r2wB, r2BT, 192, 192);
    wtrans1_kernel<<<cdiv(192*128,256),   256, 0, stream>>>(r2s, r2ST, 192*128);
    wtrans9_kernel<<<cdiv(9*256*192,256), 256, 0, stream>>>(r3wA, r3AT, 256, 192);
    wtrans9_kernel<<<cdiv(9*256*256,256), 256, 0, stream>>>(r3wB, r3BT, 256, 256);
    wtrans1_kernel<<<cdiv(256*192,256),   256, 0, stream>>>(r3s, r3ST, 256*192);
    whh_frag_kernel<<<1024, 256, 0, stream>>>(whh_f, WF);
    whh_frag_kernel<<<1024, 256, 0, stream>>>(whh_b, WF + 262144);

    // ---- frontend mask ----
    mask_partial_kernel<<<dim3(63, 32), 256, 0, stream>>>(fW, fB, P);
    mask_finalize_apply<<<63, 256, 0, stream>>>(P, x, XM);

    // ---- conv stack, chunked over batch ----
    for (int c0 = 0; c0 < 32; c0 += NC) {
        const float* xmc = XM + (size_t)c0*15903;
        conv1_kernel<<<dim3(63, 1, NC), 256, 0, stream>>>(xmc, cbw1, cbg, cbb, REG1);
        conv_mfma_kernel<<<dim3(cdiv(15903,64), 1, NC), 256, 0, stream>>>(
            REG1, w2T, nullptr, nullptr, REG2, 31, 513, 64, 0, 64, r1pg, r1pb);
        pool_nhwc_kernel<<<cdiv(NC*31*128*8,256), 256, 0, stream>>>(REG2, XP1c, 513, 128, 64, NC*31*128*8);
        conv_mfma_kernel<<<dim3(cdiv(31*128,64), 2, NC), 256, 0, stream>>>(
            XP1c, r1AT, nullptr, nullptr, REG1, 31, 128, 64, 0, 128, r1g, r1b);
        conv_mfma_kernel<<<dim3(cdiv(31*128,64), 2, NC), 256, 0, stream>>>(
            REG1, r1BT, XP1c, r1ST, REG2, 31, 128, 128, 64, 128, r2pg, r2pb);
        pool_nhwc_kernel<<<cdiv(NC*31*32*16,256), 256, 0, stream>>>(REG2, XP2c, 128, 32, 128, NC*31*32*16);
        conv_mfma_kernel<<<dim3(cdiv(31*32,64), 3, NC), 256, 0, stream>>>(
            XP2c, r2AT, nullptr, nullptr, REG1, 31, 32, 128, 0, 192, r2g, r2b);
        conv_mfma_kernel<<<dim3(cdiv(31*32,64), 3, NC), 256, 0, stream>>>(
            REG1, r2BT, XP2c, r2ST, REG2, 31, 32, 192, 128, 192, r3pg, r3pb);
        pool_nhwc_kernel<<<cdiv(NC*31*8*24,256), 256, 0, stream>>>(REG2, XP3c, 32, 8, 192, NC*31*8*24);
        conv_mfma_kernel<<<dim3(cdiv(31*8,64), 4, NC), 256, 0, stream>>>(
            XP3c, r3AT, nullptr, nullptr, REG1, 31, 8, 192, 0, 256, r3g, r3b);
        conv_mfma_kernel<<<dim3(cdiv(31*8,64), 4, NC), 256, 0, stream>>>(
            REG1, r3BT, XP3c, r3ST, REG2, 31, 8, 256, 192, 256, pbg, pbb);
        pool_nhwc_kernel<<<cdiv(NC*31*2*32,256), 256, 0, stream>>>(
            REG2, XP4 + (size_t)c0*15872, 8, 2, 256, NC*31*2*32);
    }

    // feats (32,31,512) fp32
    feats_kernel<<<1984, 256, 0, stream>>>(XP4, FE);

    // LSTM input projections -> xpT [d][t][b][j]
    gemm_bias_kernel<1><<<dim3(31, 16), 256, 0, stream>>>(FE, wih_f, bih_f, bhh_f, XPT,           992, 1024, 512);
    gemm_bias_kernel<1><<<dim3(31, 16), 256, 0, stream>>>(FE, wih_b, bih_b, bhh_b, XPT + 1015808, 992, 1024, 512);

    // fused bidirectional scan (4 blocks: dir x batch-half)
    lstm_scan_mfma<<<4, 1024, 0, stream>>>(XPT, WF, HC);

    // classifier -> d_out (32,31,722)
    gemm_bias_kernel<0><<<dim3(31, 12), 256, 0, stream>>>(HC, clsw, clsb, nullptr, out, 992, 722, 512);
}